// Round 2
// baseline (6412.226 us; speedup 1.0000x reference)
//
#include <hip/hip_runtime.h>
#include <cstddef>
#include <cstdint>

// CT-LSTM right-to-left scan. 128 independent sequences, T=256, H=256,
// 7H=1792 gate rows, VOCAB=35, IDX_PAD=34.
//
//   z = EW[event] + h @ W2^T     (EW = Emb@W1^T + b precomputed, 35x1792)
//
// LDS-resident weights: 32 teams x 8 blocks. Block owns j-slice of 32
// (224 rows x 256 k, f16 = 114.7 KB in LDS, loaded once). Team handles 4
// seqs; per-step h exchange via global double buffer + device-scope
// monotonic counter barrier. 256 blocks = 1/CU, co-resident.

typedef _Float16 hf;
typedef _Float16 h2 __attribute__((ext_vector_type(2)));
typedef _Float16 h8 __attribute__((ext_vector_type(8)));

#define HID 256
#define R7 1792
#define NPAD 34
#define TEAMS 32
#define SPT 4   // seqs per team

#define SVP(v, k) __builtin_shufflevector(v, v, 2*(k), 2*(k)+1)

__device__ __forceinline__ float fdot2_(h2 a, h2 b, float c) {
#if __has_builtin(__builtin_amdgcn_fdot2)
  return __builtin_amdgcn_fdot2(a, b, c, false);
#else
  return fmaf((float)a[0], (float)b[0], fmaf((float)a[1], (float)b[1], c));
#endif
}

__device__ __forceinline__ float sigf(float x) { return 1.0f / (1.0f + __expf(-x)); }
__device__ __forceinline__ float tanh_f(float x) { return 1.0f - 2.0f / (__expf(2.0f * x) + 1.0f); }
__device__ __forceinline__ float softplusf(float x) {
  return fmaxf(x, 0.0f) + __logf(1.0f + __expf(-fabsf(x)));
}

// ---------------------------------------------------------------------------
// Repack W[:, 256:512] (fp32 [1792][512]) -> f16, layout [slice][c][g][jj][8]:
//   dst[(((slice*32 + c)*7 + g)*32 + jj)*8 + e] = W[g*256 + slice*32 + jj][256 + 8c + e]
__global__ __launch_bounds__(256) void repack_kernel(const float* __restrict__ W,
                                                     h8* __restrict__ W2v) {
  int idx = blockIdx.x * 256 + threadIdx.x;  // [0, 57344)
  int jj  = idx & 31;
  int t   = idx >> 5;        // [0, 1792)
  int g   = t % 7;
  int t2  = t / 7;           // [0, 256) = slice*32 + c
  int c   = t2 & 31;
  int sl  = t2 >> 5;
  int r   = g * 256 + sl * 32 + jj;
  const float* src = W + (size_t)r * 512 + 256 + 8 * c;
  h8 o;
#pragma unroll
  for (int e = 0; e < 8; ++e) o[e] = (hf)src[e];
  W2v[idx] = o;
}

// ---------------------------------------------------------------------------
// EW[e][r] = Emb[e] . W[r][0:256] + b[r]
__global__ __launch_bounds__(256) void ew_kernel(const float* __restrict__ Emb,
                                                 const float* __restrict__ W,
                                                 const float* __restrict__ bias,
                                                 float* __restrict__ EW) {
  int wid  = (blockIdx.x * 256 + threadIdx.x) >> 6;
  int lane = threadIdx.x & 63;
  int o    = wid * 4;
#pragma unroll
  for (int q = 0; q < 4; ++q, ++o) {
    int e = o / R7;
    int r = o - e * R7;
    const float4 ev4 = *(const float4*)(Emb + e * HID + lane * 4);
    const float4 wv4 = *(const float4*)(W + (size_t)r * 512 + lane * 4);
    float acc = ev4.x * wv4.x + ev4.y * wv4.y + ev4.z * wv4.z + ev4.w * wv4.w;
#pragma unroll
    for (int m = 32; m >= 1; m >>= 1) acc += __shfl_xor(acc, m, 64);
    if (lane == 0) EW[o] = acc + bias[r];
  }
}

// ---------------------------------------------------------------------------
__global__ __launch_bounds__(256, 1) void scan_kernel(
    const int* __restrict__ event, const float* __restrict__ dtime,
    const float* __restrict__ EW, const h8* __restrict__ Wg,
    float* __restrict__ out, float* __restrict__ ghbuf, unsigned int* cnt) {
  const int tid   = threadIdx.x;
  const int team  = blockIdx.x & 31;   // teammates share blockIdx%32 -> same XCD (heuristic)
  const int slice = blockIdx.x >> 5;

  __shared__ __align__(16) hf wl[32][7][32][8];  // [c][g][jj][e] 114688 B
  __shared__ __align__(16) hf hl[SPT][HID];      // 2048 B
  __shared__ float zl[7][SPT][32];               // 3584 B
  __shared__ int   evl[SPT][256];                // 4096 B
  __shared__ float dtl[SPT][256];                // 4096 B

  // stage weights (once)
  {
    const h8* src = Wg + slice * 7168;
    h8* dst = (h8*)&wl[0][0][0][0];
    for (int t = tid; t < 7168; t += 256) dst[t] = src[t];
  }
  for (int t = tid; t < SPT * 256; t += 256) {
    int s = t >> 8, k = t & 255;
    int seq = team * SPT + s;
    evl[s][k] = event[seq * 256 + k];
    dtl[s][k] = dtime[seq * 256 + k];
    ((hf*)hl)[t] = (hf)0.0f;
  }
  __syncthreads();

  const int jj    = tid & 31;
  const int g     = tid >> 5;          // 0..7 (g==7 idle in compute)
  const int jglob = slice * 32 + jj;

  // per-(seq,j) recurrent state for epilogue threads (tid<128)
  float cp = 0.f, cb = 0.f;
  const int es = tid >> 5;             // seq for epilogue
  const size_t OS = 8355840;           // per-output-tensor stride

  unsigned int target = 0;
  int wp = 0;
  unsigned int* mycnt = cnt + team * 16;  // 64 B stride between teams

  float acc[SPT];
  if (g < 7) {
    const int row = g * 256 + jglob;
#pragma unroll
    for (int s = 0; s < SPT; ++s) acc[s] = EW[evl[s][255] * R7 + row];
  }

  for (int i = 255; i >= 1; --i) {
    // ---- dot: z = EW + h @ W2^T (from LDS) ----
    if (g < 7) {
#pragma unroll 2
      for (int c = 0; c < 32; ++c) {
        const h8 w = *(const h8*)&wl[c][g][jj][0];
        const h2 q0 = SVP(w, 0), q1 = SVP(w, 1), q2 = SVP(w, 2), q3 = SVP(w, 3);
#pragma unroll
        for (int s = 0; s < SPT; ++s) {
          const h8 hv = *(const h8*)&hl[s][8 * c];
          float a = acc[s];
          a = fdot2_(q0, SVP(hv, 0), a);
          a = fdot2_(q1, SVP(hv, 1), a);
          a = fdot2_(q2, SVP(hv, 2), a);
          a = fdot2_(q3, SVP(hv, 3), a);
          acc[s] = a;
        }
      }
#pragma unroll
      for (int s = 0; s < SPT; ++s) zl[g][s][jj] = acc[s];
    }
    __syncthreads();

    // ---- epilogue: tid<128 handles (seq=es, j=jglob) ----
    float* hb = ghbuf + (size_t)(wp * TEAMS + team) * (SPT * HID);
    if (tid < 128) {
      const int   ev = evl[es][i];
      const float dt = dtl[es][i];
      float gi  = sigf(zl[0][es][jj]);
      float gf  = sigf(zl[1][es][jj]);
      float go  = sigf(zl[2][es][jj]);
      float gz  = tanh_f(zl[3][es][jj]);
      float gib = sigf(zl[4][es][jj]);
      float gfb = sigf(zl[5][es][jj]);
      float gd  = softplusf(zl[6][es][jj]);
      float cell = gf * cp + gi * gz;
      float cbar = gfb * cb + gib * gz;
      float hm   = go * tanh_f(cell);
      float dec  = __expf(-gd * dt);
      float cim  = cbar + (cell - cbar) * dec;
      float him  = go * tanh_f(cim);
      float m    = (ev != NPAD) ? 1.0f : 0.0f;
      float cbm  = cbar * m;
      float hn   = him * m;
      float* o = out + (size_t)(team * SPT + es) * 65280 + (size_t)(i - 1) * HID + jglob;
      o[0] = cell; o[OS] = cbm; o[2 * OS] = gd; o[3 * OS] = go;
      o[4 * OS] = hn; o[5 * OS] = hm;
      cp = cim * m; cb = cbm;
      if (i > 1) hb[es * HID + jglob] = hn;   // publish h slice
    }

    if (i > 1) {
      __threadfence();
      __syncthreads();
      if (tid == 0) atomicAdd(mycnt, 1u);
      target += 8;
      // prefetch EW for next step while waiting (independent of h)
      if (g < 7) {
        const int row = g * 256 + jglob;
#pragma unroll
        for (int s = 0; s < SPT; ++s) acc[s] = EW[evl[s][i - 1] * R7 + row];
      }
      if (tid == 0) {
        while (__hip_atomic_load(mycnt, __ATOMIC_ACQUIRE, __HIP_MEMORY_SCOPE_AGENT) < target)
          __builtin_amdgcn_s_sleep(2);
      }
      __syncthreads();
      // stage full team h (coherent loads bypass stale caches)
#pragma unroll
      for (int q = 0; q < SPT; ++q) {
        int t = q * 256 + tid;
        float v = __hip_atomic_load(hb + t, __ATOMIC_RELAXED, __HIP_MEMORY_SCOPE_AGENT);
        ((hf*)hl)[t] = (hf)v;
      }
      __syncthreads();
      wp ^= 1;
    }
  }
}

extern "C" void kernel_launch(void* const* d_in, const int* in_sizes, int n_in,
                              void* d_out, int out_size, void* d_ws, size_t ws_size,
                              hipStream_t stream) {
  const int*   event = (const int*)d_in[0];
  const float* dtime = (const float*)d_in[1];
  const float* Emb   = (const float*)d_in[2];
  const float* W     = (const float*)d_in[3];
  const float* bias  = (const float*)d_in[4];
  float*       out   = (float*)d_out;

  char* ws = (char*)d_ws;
  hf*    W2v   = (hf*)ws;                        // 917504 B
  float* EW    = (float*)(ws + 917504);          // 250880 B
  float* ghbuf = (float*)(ws + 1168384);         // 2*32*4*256*4 = 262144 B
  unsigned int* cnt = (unsigned int*)(ws + 1430528);  // 32*64 = 2048 B

  hipMemsetAsync(cnt, 0, 2048, stream);
  repack_kernel<<<224, 256, 0, stream>>>(W, (h8*)W2v);
  ew_kernel<<<3920, 256, 0, stream>>>(Emb, W, bias, EW);
  scan_kernel<<<256, 256, 0, stream>>>(event, dtime, EW, (const h8*)W2v, out, ghbuf, cnt);
}

// Round 3
// 3567.803 us; speedup vs baseline: 1.7972x; 1.7972x over previous
//
#include <hip/hip_runtime.h>
#include <cstddef>
#include <cstdint>

// CT-LSTM right-to-left scan. 128 independent sequences, T=256, H=256,
// 7H=1792 gate rows, VOCAB=35, IDX_PAD=34.
//
//   z = EW[event] + h @ W2^T     (EW = Emb@W1^T + b precomputed, 35x1792)
//
// Round-3 structure: 64 blocks x 512 threads (1 block/CU, 8 waves/CU).
// Thread (half=tid>>8, j=tid&255) computes 7 gate rows over its k-half
// (128 k) for 2 seqs; partials reduced via LDS. Weight chunks c'∈{0,1}
// (12.5%, 114.7 KB) are LDS-resident; the rest (802 KB/step) streams from
// L2 with a register double-buffer. EW gather hoisted to step start.

typedef _Float16 hf;
typedef _Float16 h2 __attribute__((ext_vector_type(2)));
typedef _Float16 h8 __attribute__((ext_vector_type(8)));

#define HID 256
#define R7 1792
#define NPAD 34

#define SVP(v, k) __builtin_shufflevector(v, v, 2*(k), 2*(k)+1)

__device__ __forceinline__ float fdot2_(h2 a, h2 b, float c) {
#if __has_builtin(__builtin_amdgcn_fdot2)
  return __builtin_amdgcn_fdot2(a, b, c, false);
#else
  return fmaf((float)a[0], (float)b[0], fmaf((float)a[1], (float)b[1], c));
#endif
}

__device__ __forceinline__ float sigf(float x) { return 1.0f / (1.0f + __expf(-x)); }
__device__ __forceinline__ float tanh_f(float x) { return 1.0f - 2.0f / (__expf(2.0f * x) + 1.0f); }
__device__ __forceinline__ float softplusf(float x) {
  return fmaxf(x, 0.0f) + __logf(1.0f + __expf(-fabsf(x)));
}

// ---------------------------------------------------------------------------
// Repack W[:, 256:512] (fp32 [1792][512]) -> f16 chunks, layout
//   W2v[(((half*16 + c)*7 + g)*256 + j)] (h8) = W[g*256+j][256 + half*128 + 8c + e]
__global__ __launch_bounds__(256) void repack_kernel(const float* __restrict__ W,
                                                     h8* __restrict__ W2v) {
  int idx = blockIdx.x * 256 + threadIdx.x;  // [0, 57344)
  int j   = idx & 255;
  int q   = idx >> 8;        // [0, 224) = (half*16 + c)*7 + g
  int g   = q % 7;
  int hc  = q / 7;           // [0, 32)
  int c   = hc & 15;
  int half= hc >> 4;
  int r   = g * 256 + j;
  const float* src = W + (size_t)r * 512 + 256 + half * 128 + 8 * c;
  h8 o;
#pragma unroll
  for (int e = 0; e < 8; ++e) o[e] = (hf)src[e];
  W2v[idx] = o;
}

// ---------------------------------------------------------------------------
// EW[e][r] = Emb[e] . W[r][0:256] + b[r]
__global__ __launch_bounds__(256) void ew_kernel(const float* __restrict__ Emb,
                                                 const float* __restrict__ W,
                                                 const float* __restrict__ bias,
                                                 float* __restrict__ EW) {
  int wid  = (blockIdx.x * 256 + threadIdx.x) >> 6;
  int lane = threadIdx.x & 63;
  int o    = wid * 4;
#pragma unroll
  for (int q = 0; q < 4; ++q, ++o) {
    int e = o / R7;
    int r = o - e * R7;
    const float4 ev4 = *(const float4*)(Emb + e * HID + lane * 4);
    const float4 wv4 = *(const float4*)(W + (size_t)r * 512 + lane * 4);
    float acc = ev4.x * wv4.x + ev4.y * wv4.y + ev4.z * wv4.z + ev4.w * wv4.w;
#pragma unroll
    for (int m = 32; m >= 1; m >>= 1) acc += __shfl_xor(acc, m, 64);
    if (lane == 0) EW[o] = acc + bias[r];
  }
}

// ---------------------------------------------------------------------------
__global__ __launch_bounds__(512, 1) void scan_kernel(
    const int* __restrict__ event, const float* __restrict__ dtime,
    const float* __restrict__ EW, const h8* __restrict__ Wg,
    float* __restrict__ out) {
  const int tid  = threadIdx.x;
  const int j    = tid & 255;
  const int half = tid >> 8;
  const int seqb = blockIdx.x * 2;

  __shared__ __align__(16) h8 wres[2][2][7][256];  // [half][c][g][j]  114688 B
  __shared__ __align__(16) hf hl[2][2][HID];       // [buf][seq][k]      2048 B
  __shared__ float zp[2][7][2][256];               // [half][g][seq][j] 28672 B
  __shared__ int   evl[2][256];                    //                    2048 B
  __shared__ float dtl[2][256];                    //                    2048 B

  // stage resident weight chunks (c' in {0,1} for each half)
  for (int t = tid; t < 7168; t += 512) {
    int jj = t & 255;
    int q  = t >> 8;             // [0,28) = (hf*2 + c)*7 + g
    int g  = q % 7;
    int hc = q / 7;              // [0,4)
    int c  = hc & 1;
    int hh = hc >> 1;
    ((h8*)wres)[t] = Wg[((hh * 16 + c) * 7 + g) * 256 + jj];
  }
  {
    int s = tid >> 8, k = tid & 255;
    evl[s][k] = event[(seqb + s) * 256 + k];
    dtl[s][k] = dtime[(seqb + s) * 256 + k];
    hl[0][s][k] = (hf)0.0f;
  }
  __syncthreads();

  float cp_s = 0.f, cb_s = 0.f;   // epilogue recurrent state: (seq=half, j)
  int rb = 0;
  const size_t OS = 8355840;      // per-output-tensor stride

  for (int i = 255; i >= 1; --i) {
    // --- EW prefetch for epilogue (independent of h) ---
    const int ev_e = evl[half][i];
    float ew[7];
#pragma unroll
    for (int g = 0; g < 7; ++g) ew[g] = EW[ev_e * R7 + g * HID + j];

    // --- prefetch first streamed chunk group (c'=2) ---
    const h8* p = Wg + (size_t)((half * 16 + 2) * 7) * 256 + j;
    h8 wa[7], wb[7];
#pragma unroll
    for (int g = 0; g < 7; ++g) wa[g] = p[g * 256];

    float a0[7], a1[7];
#pragma unroll
    for (int g = 0; g < 7; ++g) { a0[g] = 0.f; a1[g] = 0.f; }

    const h8* h0 = (const h8*)hl[rb][0];
    const h8* h1 = (const h8*)hl[rb][1];

    // --- resident part: c' in {0,1} ---
#pragma unroll
    for (int c = 0; c < 2; ++c) {
      const h8 hv0 = h0[half * 16 + c];
      const h8 hv1 = h1[half * 16 + c];
#pragma unroll
      for (int g = 0; g < 7; ++g) {
        const h8 w = wres[half][c][g][j];
        const h2 q0 = SVP(w, 0), q1 = SVP(w, 1), q2 = SVP(w, 2), q3 = SVP(w, 3);
        float s0 = a0[g];
        s0 = fdot2_(q0, SVP(hv0, 0), s0);
        s0 = fdot2_(q1, SVP(hv0, 1), s0);
        s0 = fdot2_(q2, SVP(hv0, 2), s0);
        s0 = fdot2_(q3, SVP(hv0, 3), s0);
        a0[g] = s0;
        float s1 = a1[g];
        s1 = fdot2_(q0, SVP(hv1, 0), s1);
        s1 = fdot2_(q1, SVP(hv1, 1), s1);
        s1 = fdot2_(q2, SVP(hv1, 2), s1);
        s1 = fdot2_(q3, SVP(hv1, 3), s1);
        a1[g] = s1;
      }
    }

    // --- streamed part: c' in [2,16), register double-buffer ---
#pragma unroll
    for (int c = 2; c < 16; ++c) {
      h8* cur = ((c & 1) == 0) ? wa : wb;
      h8* nxt = ((c & 1) == 0) ? wb : wa;
      if (c < 15) {
        const h8* pn = p + 1792;
#pragma unroll
        for (int g = 0; g < 7; ++g) nxt[g] = pn[g * 256];
      }
      const h8 hv0 = h0[half * 16 + c];
      const h8 hv1 = h1[half * 16 + c];
#pragma unroll
      for (int g = 0; g < 7; ++g) {
        const h8 w = cur[g];
        const h2 q0 = SVP(w, 0), q1 = SVP(w, 1), q2 = SVP(w, 2), q3 = SVP(w, 3);
        float s0 = a0[g];
        s0 = fdot2_(q0, SVP(hv0, 0), s0);
        s0 = fdot2_(q1, SVP(hv0, 1), s0);
        s0 = fdot2_(q2, SVP(hv0, 2), s0);
        s0 = fdot2_(q3, SVP(hv0, 3), s0);
        a0[g] = s0;
        float s1 = a1[g];
        s1 = fdot2_(q0, SVP(hv1, 0), s1);
        s1 = fdot2_(q1, SVP(hv1, 1), s1);
        s1 = fdot2_(q2, SVP(hv1, 2), s1);
        s1 = fdot2_(q3, SVP(hv1, 3), s1);
        a1[g] = s1;
      }
      p += 1792;
    }

#pragma unroll
    for (int g = 0; g < 7; ++g) { zp[half][g][0][j] = a0[g]; zp[half][g][1][j] = a1[g]; }
    __syncthreads();

    // --- epilogue: thread handles (seq = half, j) ---
    {
      const float dt = dtl[half][i];
      float z[7];
#pragma unroll
      for (int g = 0; g < 7; ++g) z[g] = zp[0][g][half][j] + zp[1][g][half][j] + ew[g];
      float gi  = sigf(z[0]);
      float gf  = sigf(z[1]);
      float go  = sigf(z[2]);
      float gz  = tanh_f(z[3]);
      float gib = sigf(z[4]);
      float gfb = sigf(z[5]);
      float gd  = softplusf(z[6]);
      float cell = gf * cp_s + gi * gz;
      float cbar = gfb * cb_s + gib * gz;
      float hm   = go * tanh_f(cell);
      float dec  = __expf(-gd * dt);
      float cim  = cbar + (cell - cbar) * dec;
      float him  = go * tanh_f(cim);
      float m    = (ev_e != NPAD) ? 1.0f : 0.0f;
      float cbm  = cbar * m;
      float hn   = him * m;
      float* o = out + (size_t)(seqb + half) * 65280 + (size_t)(i - 1) * HID + j;
      o[0] = cell; o[OS] = cbm; o[2 * OS] = gd; o[3 * OS] = go;
      o[4 * OS] = hn; o[5 * OS] = hm;
      cp_s = cim * m; cb_s = cbm;
      hl[rb ^ 1][half][j] = (hf)hn;
    }
    __syncthreads();
    rb ^= 1;
  }
}

extern "C" void kernel_launch(void* const* d_in, const int* in_sizes, int n_in,
                              void* d_out, int out_size, void* d_ws, size_t ws_size,
                              hipStream_t stream) {
  const int*   event = (const int*)d_in[0];
  const float* dtime = (const float*)d_in[1];
  const float* Emb   = (const float*)d_in[2];
  const float* W     = (const float*)d_in[3];
  const float* bias  = (const float*)d_in[4];
  float*       out   = (float*)d_out;

  char* ws = (char*)d_ws;
  hf*    W2v = (hf*)ws;                 // 917504 B
  float* EW  = (float*)(ws + 917504);   // 250880 B

  repack_kernel<<<224, 256, 0, stream>>>(W, (h8*)W2v);
  ew_kernel<<<3920, 256, 0, stream>>>(Emb, W, bias, EW);
  scan_kernel<<<64, 512, 0, stream>>>(event, dtime, EW, (const h8*)W2v, out);
}